// Round 7
// baseline (1499.799 us; speedup 1.0000x reference)
//
#include <hip/hip_runtime.h>

// ---------------------------------------------------------------------------
// HierarchicalBiLSTM_CRF on MI355X (gfx950) — round 7
//
// Round-7: software-pipelined recurrent kernels.
//  - Whh kt0-1 LDS-resident (128 KB); kt2-7 streamed via ping-pong register
//    buffers (load next section before MFMA of current; next step's first
//    section prefetched before the epilogue — weights are step-invariant).
//  - gx loads issued at step start (MFMA phase covers HBM latency); gxs/gxc
//    transposed to t-major layout (step's gx = contiguous 32 KB).
// ---------------------------------------------------------------------------

typedef __attribute__((ext_vector_type(8))) short s16x8;
typedef __attribute__((ext_vector_type(4))) float f32x4;
typedef __attribute__((ext_vector_type(2))) unsigned int u32x2;

__device__ __forceinline__ unsigned short f2bf(float f) {
  unsigned u = __builtin_bit_cast(unsigned, f);
  u += 0x7fff + ((u >> 16) & 1);   // RNE
  return (unsigned short)(u >> 16);
}
__device__ __forceinline__ float bf2f(unsigned short h) {
  unsigned u = ((unsigned)h) << 16;
  return __builtin_bit_cast(float, u);
}
__device__ __forceinline__ float sigm(float x) { return 1.f / (1.f + __expf(-x)); }
__device__ __forceinline__ float tanh_(float x) { return 1.f - 2.f / (__expf(2.f * x) + 1.f); }

union PK8 { s16x8 v; unsigned short u[8]; };

#define LOADSEC(buf, kt) { _Pragma("unroll") \
  for (int g = 0; g < 4; ++g) buf[g] = *(const s16x8*)&wgl[((kt) * 8 + g * 2) * 512]; }

#define MFMASEC(kt, buf) { \
  s16x8 a0 = *(const s16x8*)&hly[cc * 264 + (kt) * 32 + qq * 8]; \
  s16x8 a1 = *(const s16x8*)&hly[(16 + cc) * 264 + (kt) * 32 + qq * 8]; \
  _Pragma("unroll") for (int g = 0; g < 4; ++g) { \
    acc[0][g] = __builtin_amdgcn_mfma_f32_16x16x32_bf16(a0, buf[g], acc[0][g], 0, 0, 0); \
    acc[1][g] = __builtin_amdgcn_mfma_f32_16x16x32_bf16(a1, buf[g], acc[1][g], 0, 0, 0); } }

#define MFMALDS(kt) { \
  s16x8 a0 = *(const s16x8*)&hly[cc * 264 + (kt) * 32 + qq * 8]; \
  s16x8 a1 = *(const s16x8*)&hly[(16 + cc) * 264 + (kt) * 32 + qq * 8]; \
  _Pragma("unroll") for (int g = 0; g < 4; ++g) { \
    s16x8 bf = *(const s16x8*)&ldw[((kt) * 4 + g) * 512]; \
    acc[0][g] = __builtin_amdgcn_mfma_f32_16x16x32_bf16(a0, bf, acc[0][g], 0, 0, 0); \
    acc[1][g] = __builtin_amdgcn_mfma_f32_16x16x32_bf16(a1, bf, acc[1][g], 0, 0, 0); } }

// ---------------------------------------------------------------------------
// K0a: cast input-projection weights to bf16 (pad K 300->320 for token Wih)
__global__ void prep_weights(const float* __restrict__ wihf, const float* __restrict__ wihb,
                             const float* __restrict__ wcf, const float* __restrict__ wcb,
                             unsigned short* __restrict__ o_wf, unsigned short* __restrict__ o_wb,
                             unsigned short* __restrict__ o_wcf, unsigned short* __restrict__ o_wcb) {
  const int job = blockIdx.y, r = blockIdx.x, tid = threadIdx.x;
  const float* src; unsigned short* dst; int Ks, Kd;
  switch (job) {
    case 0: src = wihf; dst = o_wf;   Ks = 300; Kd = 320; break;
    case 1: src = wihb; dst = o_wb;   Ks = 300; Kd = 320; break;
    case 2: src = wcf;  dst = o_wcf;  Ks = 512; Kd = 512; break;
    default:src = wcb;  dst = o_wcb;  Ks = 512; Kd = 512; break;
  }
  for (int c = tid; c < Kd; c += 256)
    dst[r * Kd + c] = f2bf(c < Ks ? src[r * Ks + c] : 0.f);
}

// ---------------------------------------------------------------------------
// K0c: repack recurrent weights [1024][256] f32 -> fragment-major bf16.
__global__ __launch_bounds__(256)
void prep_whh_frag(const float* __restrict__ w0, const float* __restrict__ w1,
                   const float* __restrict__ w2,
                   unsigned short* __restrict__ o0, unsigned short* __restrict__ o1,
                   unsigned short* __restrict__ o2) {
  const float* src = blockIdx.y == 0 ? w0 : (blockIdx.y == 1 ? w1 : w2);
  unsigned short* dst = blockIdx.y == 0 ? o0 : (blockIdx.y == 1 ? o1 : o2);
  const int fid = blockIdx.x;
  const int b = fid & 1, g = (fid >> 1) & 3, kt = (fid >> 3) & 7, js = fid >> 6;
  for (int i = threadIdx.x; i < 512; i += 256) {
    const int lane = i >> 3, e = i & 7;
    const int cc = lane & 15, qq = lane >> 4;
    const int row = g * 256 + (js * 2 + b) * 16 + cc;
    const int col = kt * 32 + qq * 8 + e;
    dst[(size_t)fid * 512 + i] = f2bf(src[row * 256 + col]);
  }
}

// ---------------------------------------------------------------------------
__global__ void prep_small(const int* __restrict__ x, const int* __restrict__ xcl,
                           int* __restrict__ clens, int* __restrict__ lastv,
                           int* __restrict__ order, int* __restrict__ glen) {
  __shared__ int start[65];
  const int n = threadIdx.x;  // 1024 threads
  if (n < 65) start[n] = 0;
  __syncthreads();
  int len = xcl[n]; len = len < 1 ? 1 : (len > 64 ? 64 : len);
  clens[n] = len;
  lastv[n] = x[n * 64 + len - 1];
  atomicAdd(&start[len], 1);
  __syncthreads();
  if (n == 0) {
    int acc = 0;
    for (int l = 64; l >= 1; --l) { int h = start[l]; start[l] = acc; acc += h; }
  }
  __syncthreads();
  int pos = atomicAdd(&start[len], 1);
  order[pos] = n;
  __syncthreads();
  if (n < 32) glen[n] = clens[order[n * 32]];   // descending -> first = group max
}

// ---------------------------------------------------------------------------
// Unified GEMM: C[M][1024](bf16) = A(rows via rowmap)[M][Klog](f32) x B[1024][KP](bf16)^T
__global__ __launch_bounds__(256, 2)
void gemm_bf(const float* __restrict__ A, const int* __restrict__ rowmap,
             int Mrows, int Astride, int Klog, int KP,
             const unsigned short* __restrict__ B, unsigned short* __restrict__ C) {
  __shared__ unsigned short As[128 * 40];
  __shared__ unsigned short Ep[4][64 * 136];
  const int tid = threadIdx.x;
  const int lane = tid & 63, w = tid >> 6;
  const int wrow = w >> 1, wcol = w & 1;
  const int cc = lane & 15, qq = lane >> 4;
  const int m0 = blockIdx.y * 128, n0 = blockIdx.x * 256;

  f32x4 zz = {0.f, 0.f, 0.f, 0.f};
  f32x4 acc[4][8];
#pragma unroll
  for (int i = 0; i < 4; ++i)
#pragma unroll
    for (int j = 0; j < 8; ++j) acc[i][j] = zz;

  const int arow = tid >> 1, ahalf = tid & 1;
  const float* arp = nullptr;
  {
    int av = m0 + arow;
    if (av < Mrows) {
      int amap = rowmap ? rowmap[av] : av;
      arp = A + (long)amap * Astride;
    }
  }

  const int nktiles = KP >> 5;
  for (int kt = 0; kt < nktiles; ++kt) {
    const int k0 = kt << 5;
    __syncthreads();
    {
      const int kb = k0 + ahalf * 16;
      unsigned short hv[16];
      if (arp && kb + 16 <= Klog) {
        const float* p = arp + kb;
#pragma unroll
        for (int i = 0; i < 16; i += 4) {
          f32x4 t = *(const f32x4*)(p + i);
          hv[i] = f2bf(t.x); hv[i + 1] = f2bf(t.y);
          hv[i + 2] = f2bf(t.z); hv[i + 3] = f2bf(t.w);
        }
      } else {
#pragma unroll
        for (int i = 0; i < 16; ++i) {
          float v = (arp && (kb + i) < Klog) ? arp[kb + i] : 0.f;
          hv[i] = f2bf(v);
        }
      }
      PK8 p0, p1;
#pragma unroll
      for (int i = 0; i < 8; ++i) { p0.u[i] = hv[i]; p1.u[i] = hv[8 + i]; }
      *(s16x8*)&As[arow * 40 + ahalf * 16] = p0.v;
      *(s16x8*)&As[arow * 40 + ahalf * 16 + 8] = p1.v;
    }
    __syncthreads();
    s16x8 af[4];
#pragma unroll
    for (int mt = 0; mt < 4; ++mt)
      af[mt] = *(const s16x8*)&As[(wrow * 64 + mt * 16 + cc) * 40 + qq * 8];
#pragma unroll
    for (int nt = 0; nt < 8; ++nt) {
      const unsigned short* bp = B + (long)(n0 + wcol * 128 + nt * 16 + cc) * KP + k0 + qq * 8;
      s16x8 bfr = *(const s16x8*)bp;
#pragma unroll
      for (int mt = 0; mt < 4; ++mt)
        acc[mt][nt] = __builtin_amdgcn_mfma_f32_16x16x32_bf16(af[mt], bfr, acc[mt][nt], 0, 0, 0);
    }
  }
  __syncthreads();
#pragma unroll
  for (int mt = 0; mt < 4; ++mt)
#pragma unroll
    for (int nt = 0; nt < 8; ++nt)
#pragma unroll
      for (int r = 0; r < 4; ++r)
        Ep[w][(mt * 16 + qq * 4 + r) * 136 + nt * 16 + cc] = f2bf(acc[mt][nt][r]);
  __syncthreads();
#pragma unroll
  for (int it = 0; it < 16; ++it) {
    int row = it * 4 + qq;
    s16x8 d = *(const s16x8*)&Ep[w][row * 136 + cc * 8];
    int gm = m0 + wrow * 64 + row;
    int gn = n0 + wcol * 128 + cc * 8;
    if (gm < Mrows) *(s16x8*)&C[(long)gm * 1024 + gn] = d;
  }
}

// ---------------------------------------------------------------------------
__global__ void bwd_step(const unsigned short* __restrict__ gxb,
                         const float* __restrict__ bias,
                         float* __restrict__ chunks) {
  const int n = blockIdx.x, j = threadIdx.x;  // 1024 x 256
  const unsigned short* row = gxb + (long)n * 1024;
  float gi = bf2f(row[j]) + bias[j];
  float gg = bf2f(row[512 + j]) + bias[512 + j];
  float go = bf2f(row[768 + j]) + bias[768 + j];
  float cn = sigm(gi) * tanh_(gg);
  chunks[(long)n * 512 + 256 + j] = sigm(go) * tanh_(cn);
}

// ---------------------------------------------------------------------------
// K4: pre-gather gate projections (gate-packed, bias folded), sorted order,
// T-MAJOR layout: gx[gb][t][m][j*4+g].
__global__ __launch_bounds__(256)
void gather_gx(const unsigned short* __restrict__ proj, const int* __restrict__ x,
               const int* __restrict__ order, const int* __restrict__ clens,
               const int* __restrict__ glen, const float* __restrict__ bias,
               unsigned short* __restrict__ gx) {
  const int t = blockIdx.x, p = blockIdx.y, j = threadIdx.x;
  if (t >= glen[p >> 5]) return;
  const int seq = order[p];
  const int len = clens[seq];
  unsigned short* dst = gx + (((size_t)(p >> 5) * 64 + t) * 32 + (p & 31)) * 1024 + j * 4;
  if (t >= len) { u32x2 z = {0u, 0u}; *(u32x2*)dst = z; return; }
  const int tok = x[seq * 64 + t];
  const unsigned short* src = proj + (size_t)tok * 1024 + j;
  unsigned v0 = f2bf(bf2f(src[0]) + bias[j]);
  unsigned v1 = f2bf(bf2f(src[256]) + bias[256 + j]);
  unsigned v2 = f2bf(bf2f(src[512]) + bias[512 + j]);
  unsigned v3 = f2bf(bf2f(src[768]) + bias[768 + j]);
  u32x2 pk = {v0 | (v1 << 16), v2 | (v3 << 16)};
  *(u32x2*)dst = pk;
}

// ---------------------------------------------------------------------------
// K6b: gate-pack gxc with bias folded, T-MAJOR: dst[(t*32+m)] from src[m*32+t]
__global__ __launch_bounds__(256)
void repack4(const unsigned short* __restrict__ s0, const unsigned short* __restrict__ s1,
             const float* __restrict__ b0, const float* __restrict__ b1,
             unsigned short* __restrict__ d0, unsigned short* __restrict__ d1) {
  const int r = blockIdx.x, j = threadIdx.x;
  const int m = r >> 5, t = r & 31;
  const unsigned short* s = (blockIdx.y ? s1 : s0) + (size_t)r * 1024;
  const float* bb = blockIdx.y ? b1 : b0;
  unsigned short* d = (blockIdx.y ? d1 : d0) + (size_t)(t * 32 + m) * 1024 + j * 4;
  unsigned v0 = f2bf(bf2f(s[j]) + bb[j]);
  unsigned v1 = f2bf(bf2f(s[256 + j]) + bb[256 + j]);
  unsigned v2 = f2bf(bf2f(s[512 + j]) + bb[512 + j]);
  unsigned v3 = f2bf(bf2f(s[768 + j]) + bb[768 + j]);
  u32x2 pk = {v0 | (v1 << 16), v2 | (v3 << 16)};
  *(u32x2*)d = pk;
}

// ---------------------------------------------------------------------------
// K5: forward token LSTM. 32 blocks x 1024 threads (16 waves, 4/SIMD).
// Whh: kt0-1 LDS / kt2-7 ping-pong streamed. gx loaded at step start.
__global__ __launch_bounds__(1024, 4)
void tok_fwd(const unsigned short* __restrict__ gx,     // [gb][64][32][1024] packed+bias
             const unsigned short* __restrict__ WhP,    // fragment-major
             const int* __restrict__ order,
             const int* __restrict__ clens,
             const int* __restrict__ glen,
             float* __restrict__ chunks) {
  extern __shared__ unsigned short smem[];
  unsigned short* hly = smem;                 // [32][264] = 8448 shorts
  unsigned short* ldsW = smem + 8448;         // 16 waves * 4096 shorts (128 KB)
  int* sg = (int*)(smem + 73984);             // [32]
  int* slen = sg + 32;                        // [32]

  const int tid = threadIdx.x;
  const int lane = tid & 63, w = tid >> 6;
  const int cc = lane & 15, qq = lane >> 4;
  const int gb = blockIdx.x;

  if (tid < 32) {
    int s = order[gb * 32 + tid];
    sg[tid] = s;
    slen[tid] = clens[s];
  }
  for (int i = tid; i < 8448; i += 1024) hly[i] = 0;

  const unsigned short* wgl = WhP + ((size_t)(w >> 1) * 64 + (w & 1)) * 512 + lane * 8;
  // LDS-resident kt0-1 (8 frags/wave)
  {
    unsigned short* ld = ldsW + w * 4096 + lane * 8;
#pragma unroll
    for (int kt = 0; kt < 2; ++kt)
#pragma unroll
      for (int g = 0; g < 4; ++g)
        *(s16x8*)&ld[(kt * 4 + g) * 512] = *(const s16x8*)&wgl[(kt * 8 + g * 2) * 512];
  }

  __syncthreads();

  const int maxlen = glen[gb];
  const int j = w * 16 + cc;
  int lenr[2][4];
#pragma unroll
  for (int mt = 0; mt < 2; ++mt)
#pragma unroll
    for (int r = 0; r < 4; ++r) lenr[mt][r] = slen[mt * 16 + qq * 4 + r];

  float cst[2][4];
#pragma unroll
  for (int mt = 0; mt < 2; ++mt)
#pragma unroll
    for (int r = 0; r < 4; ++r) cst[mt][r] = 0.f;

  const unsigned short* gx0 = gx + (size_t)gb * 64 * 32 * 1024 + j * 4;
  const unsigned short* ldw = ldsW + w * 4096 + lane * 8;
  f32x4 zz = {0.f, 0.f, 0.f, 0.f};

  // preload first streamed section (kt2)
  s16x8 Sa[4], Sb[4];
  LOADSEC(Sa, 2)

  for (int t = 0; t < maxlen; ++t) {
    __syncthreads();   // A: prev-step h writes visible

    // gx loads for this step — issued early, consumed in epilogue
    u32x2 gxp[2][4];
#pragma unroll
    for (int mt = 0; mt < 2; ++mt)
#pragma unroll
      for (int r = 0; r < 4; ++r) {
        const int m = mt * 16 + qq * 4 + r;
        gxp[mt][r] = *(const u32x2*)(gx0 + ((size_t)t * 32 + m) * 1024);
      }

    f32x4 acc[2][4];
#pragma unroll
    for (int mt = 0; mt < 2; ++mt)
#pragma unroll
      for (int g = 0; g < 4; ++g) acc[mt][g] = zz;

    MFMALDS(0)
    MFMALDS(1)
    LOADSEC(Sb, 3)  MFMASEC(2, Sa)
    LOADSEC(Sa, 4)  MFMASEC(3, Sb)
    LOADSEC(Sb, 5)  MFMASEC(4, Sa)
    LOADSEC(Sa, 6)  MFMASEC(5, Sb)
    LOADSEC(Sb, 7)  MFMASEC(6, Sa)
    LOADSEC(Sa, 2)  MFMASEC(7, Sb)   // Sa prefetched for next step

    __syncthreads();   // B: MFMA h reads done

#pragma unroll
    for (int mt = 0; mt < 2; ++mt)
#pragma unroll
      for (int r = 0; r < 4; ++r) {
        const int m = mt * 16 + qq * 4 + r;
        const u32x2 pk = gxp[mt][r];
        float gi = acc[mt][0][r] + bf2f((unsigned short)(pk.x & 0xffff));
        float gf = acc[mt][1][r] + bf2f((unsigned short)(pk.x >> 16));
        float gg = acc[mt][2][r] + bf2f((unsigned short)(pk.y & 0xffff));
        float go = acc[mt][3][r] + bf2f((unsigned short)(pk.y >> 16));
        if (t < lenr[mt][r]) {
          float cn = sigm(gf) * cst[mt][r] + sigm(gi) * tanh_(gg);
          cst[mt][r] = cn;
          float hn = sigm(go) * tanh_(cn);
          hly[m * 264 + j] = f2bf(hn);
        }
      }
  }

  __syncthreads();
  // final h (frozen in hly at each sequence's last valid step) -> chunks f32
#pragma unroll
  for (int mt = 0; mt < 2; ++mt)
#pragma unroll
    for (int r = 0; r < 4; ++r) {
      const int m = mt * 16 + qq * 4 + r;
      chunks[(size_t)sg[m] * 512 + j] = bf2f(hly[m * 264 + j]);
    }
}

// ---------------------------------------------------------------------------
// K7: chunk BiLSTM. 2 blocks (dir) x 1024 threads, same pipeline.
__global__ __launch_bounds__(1024, 4)
void chunk_rec(const unsigned short* __restrict__ gxf,   // t-major packed+bias
               const unsigned short* __restrict__ gxb,
               const unsigned short* __restrict__ WhPf,
               const unsigned short* __restrict__ WhPb,
               const int* __restrict__ xlen,
               unsigned short* __restrict__ ch) {
  extern __shared__ unsigned short smem[];
  unsigned short* hly = smem;                 // 8448 shorts
  unsigned short* ldsW = smem + 8448;         // 65536 shorts

  const int tid = threadIdx.x;
  const int lane = tid & 63, w = tid >> 6;
  const int cc = lane & 15, qq = lane >> 4;
  const int dir = blockIdx.x;
  const unsigned short* gx = dir ? gxb : gxf;
  const unsigned short* WhP = dir ? WhPb : WhPf;

  for (int i = tid; i < 8448; i += 1024) hly[i] = 0;

  const unsigned short* wgl = WhP + ((size_t)(w >> 1) * 64 + (w & 1)) * 512 + lane * 8;
  {
    unsigned short* ld = ldsW + w * 4096 + lane * 8;
#pragma unroll
    for (int kt = 0; kt < 2; ++kt)
#pragma unroll
      for (int g = 0; g < 4; ++g)
        *(s16x8*)&ld[(kt * 4 + g) * 512] = *(const s16x8*)&wgl[(kt * 8 + g * 2) * 512];
  }

  __syncthreads();

  const int j = w * 16 + cc;
  int lenr[2][4];
#pragma unroll
  for (int mt = 0; mt < 2; ++mt)
#pragma unroll
    for (int r = 0; r < 4; ++r) {
      int L = xlen[mt * 16 + qq * 4 + r];
      lenr[mt][r] = L > 32 ? 32 : L;
    }

  float cst[2][4];
#pragma unroll
  for (int mt = 0; mt < 2; ++mt)
#pragma unroll
    for (int r = 0; r < 4; ++r) cst[mt][r] = 0.f;

  const unsigned short* ldw = ldsW + w * 4096 + lane * 8;
  f32x4 zz = {0.f, 0.f, 0.f, 0.f};

  s16x8 Sa[4], Sb[4];
  LOADSEC(Sa, 2)

  for (int tt = 0; tt < 32; ++tt) {
    const int t = dir ? (31 - tt) : tt;

    __syncthreads();

    u32x2 gxp[2][4];
#pragma unroll
    for (int mt = 0; mt < 2; ++mt)
#pragma unroll
      for (int r = 0; r < 4; ++r) {
        const int m = mt * 16 + qq * 4 + r;
        gxp[mt][r] = *(const u32x2*)(gx + ((size_t)t * 32 + m) * 1024 + j * 4);
      }

    f32x4 acc[2][4];
#pragma unroll
    for (int mt = 0; mt < 2; ++mt)
#pragma unroll
      for (int g = 0; g < 4; ++g) acc[mt][g] = zz;

    MFMALDS(0)
    MFMALDS(1)
    LOADSEC(Sb, 3)  MFMASEC(2, Sa)
    LOADSEC(Sa, 4)  MFMASEC(3, Sb)
    LOADSEC(Sb, 5)  MFMASEC(4, Sa)
    LOADSEC(Sa, 6)  MFMASEC(5, Sb)
    LOADSEC(Sb, 7)  MFMASEC(6, Sa)
    LOADSEC(Sa, 2)  MFMASEC(7, Sb)

    __syncthreads();

#pragma unroll
    for (int mt = 0; mt < 2; ++mt)
#pragma unroll
      for (int r = 0; r < 4; ++r) {
        const int m = mt * 16 + qq * 4 + r;
        const u32x2 pk = gxp[mt][r];
        float gi = acc[mt][0][r] + bf2f((unsigned short)(pk.x & 0xffff));
        float gf = acc[mt][1][r] + bf2f((unsigned short)(pk.x >> 16));
        float gg = acc[mt][2][r] + bf2f((unsigned short)(pk.y & 0xffff));
        float go = acc[mt][3][r] + bf2f((unsigned short)(pk.y >> 16));
        unsigned short hb16 = 0;
        if (t < lenr[mt][r]) {
          float cn = sigm(gf) * cst[mt][r] + sigm(gi) * tanh_(gg);
          cst[mt][r] = cn;
          float hn = sigm(go) * tanh_(cn);
          hb16 = f2bf(hn);
          hly[m * 264 + j] = hb16;
        }
        ch[(size_t)(m * 32 + t) * 512 + dir * 256 + j] = hb16;
      }
  }
}

// ---------------------------------------------------------------------------
__global__ __launch_bounds__(64)
void fc_kernel(const unsigned short* __restrict__ ch, const float* __restrict__ W,
               const float* __restrict__ bfc, float* __restrict__ out) {
  const int n = blockIdx.x, lane = threadIdx.x;
  float xv[8];
  const unsigned short* cp = ch + (long)n * 512 + lane * 8;
#pragma unroll
  for (int i = 0; i < 8; ++i) xv[i] = bf2f(cp[i]);
  float s[9];
#pragma unroll
  for (int k = 0; k < 9; ++k) {
    const float* wr = W + k * 512 + lane * 8;
    float t = 0.f;
#pragma unroll
    for (int i = 0; i < 8; ++i) t += xv[i] * wr[i];
    s[k] = t;
  }
#pragma unroll
  for (int off = 32; off; off >>= 1)
#pragma unroll
    for (int k = 0; k < 9; ++k) s[k] += __shfl_down(s[k], off, 64);
  if (lane == 0) {
#pragma unroll
    for (int k = 0; k < 9; ++k) out[n * 9 + k] = s[k] + bfc[k];
  }
}

// ---------------------------------------------------------------------------
extern "C" void kernel_launch(void* const* d_in, const int* in_sizes, int n_in,
                              void* d_out, int out_size, void* d_ws, size_t ws_size,
                              hipStream_t stream) {
  const int*   x           = (const int*)d_in[0];
  const int*   x_len       = (const int*)d_in[2];
  const int*   x_chunk_len = (const int*)d_in[3];
  const float* emb         = (const float*)d_in[4];
  const float* tok_Wih_f   = (const float*)d_in[5];
  const float* tok_Whh_f   = (const float*)d_in[6];
  const float* tok_b_f     = (const float*)d_in[7];
  const float* tok_Wih_b   = (const float*)d_in[8];
  // d_in[9] tok_Whh_b: unused (reverse masked scan at t=clen-1 starts from zero state)
  const float* tok_b_b     = (const float*)d_in[10];
  const float* chk_Wih_f   = (const float*)d_in[11];
  const float* chk_Whh_f   = (const float*)d_in[12];
  const float* chk_b_f     = (const float*)d_in[13];
  const float* chk_Wih_b   = (const float*)d_in[14];
  const float* chk_Whh_b   = (const float*)d_in[15];
  const float* chk_b_b     = (const float*)d_in[16];
  const float* fc_W        = (const float*)d_in[17];
  const float* fc_b        = (const float*)d_in[18];
  float* out = (float*)d_out;

  char* ws = (char*)d_ws;
  size_t off = 0;
  auto alloc = [&](size_t bytes) -> void* {
    void* p = ws + off;
    off += (bytes + 255) & ~(size_t)255;
    return p;
  };
  unsigned short* Wf   = (unsigned short*)alloc((size_t)1024 * 320 * 2);
  unsigned short* Wb   = (unsigned short*)alloc((size_t)1024 * 320 * 2);
  unsigned short* Wcf  = (unsigned short*)alloc((size_t)1024 * 512 * 2);
  unsigned short* Wcb  = (unsigned short*)alloc((size_t)1024 * 512 * 2);
  unsigned short* WhPtok=(unsigned short*)alloc((size_t)512 * 512 * 2);   // frag-major
  unsigned short* WhPcf= (unsigned short*)alloc((size_t)512 * 512 * 2);
  unsigned short* WhPcb= (unsigned short*)alloc((size_t)512 * 512 * 2);
  unsigned short* proj = (unsigned short*)alloc((size_t)30000 * 1024 * 2);
  unsigned short* gxbb = (unsigned short*)alloc((size_t)1024 * 1024 * 2);
  unsigned short* gxcf = (unsigned short*)alloc((size_t)1024 * 1024 * 2);
  unsigned short* gxcb = (unsigned short*)alloc((size_t)1024 * 1024 * 2);
  unsigned short* gxcfp= (unsigned short*)alloc((size_t)1024 * 1024 * 2);
  unsigned short* gxcbp= (unsigned short*)alloc((size_t)1024 * 1024 * 2);
  float*          chunks = (float*)alloc((size_t)1024 * 512 * 4);
  unsigned short* cho  = (unsigned short*)alloc((size_t)1024 * 512 * 2);
  unsigned short* gxs  = (unsigned short*)alloc((size_t)1024 * 64 * 1024 * 2);  // 134 MB
  int* clens = (int*)alloc(1024 * 4);
  int* lastv = (int*)alloc(1024 * 4);
  int* order = (int*)alloc(1024 * 4);
  int* glen  = (int*)alloc(32 * 4);

  // allow >64 KB dynamic LDS for the recurrent kernels (gfx950: 160 KB/CU)
  hipFuncSetAttribute((const void*)tok_fwd,
                      hipFuncAttributeMaxDynamicSharedMemorySize, 148224);
  hipFuncSetAttribute((const void*)chunk_rec,
                      hipFuncAttributeMaxDynamicSharedMemorySize, 147968);

  prep_weights<<<dim3(1024, 4), 256, 0, stream>>>(
      tok_Wih_f, tok_Wih_b, chk_Wih_f, chk_Wih_b, Wf, Wb, Wcf, Wcb);
  prep_whh_frag<<<dim3(512, 3), 256, 0, stream>>>(
      tok_Whh_f, chk_Whh_f, chk_Whh_b, WhPtok, WhPcf, WhPcb);
  prep_small<<<1, 1024, 0, stream>>>(x, x_chunk_len, clens, lastv, order, glen);

  // vocab pre-projection: proj = emb x tok_Wih_f^T
  gemm_bf<<<dim3(4, 235), 256, 0, stream>>>(emb, nullptr, 30000, 300, 300, 320, Wf, proj);
  // backward gx for last tokens only
  gemm_bf<<<dim3(4, 8), 256, 0, stream>>>(emb, lastv, 1024, 300, 300, 320, Wb, gxbb);
  bwd_step<<<1024, 256, 0, stream>>>(gxbb, tok_b_b, chunks);
  // pre-gather forward gate projections (gate-packed, bias folded, t-major)
  gather_gx<<<dim3(64, 1024), 256, 0, stream>>>(proj, x, order, clens, glen, tok_b_f, gxs);
  // forward token recurrence
  tok_fwd<<<32, 1024, 148224, stream>>>(gxs, WhPtok, order, clens, glen, chunks);
  // chunk-level input projections
  gemm_bf<<<dim3(4, 8), 256, 0, stream>>>(chunks, nullptr, 1024, 512, 512, 512, Wcf, gxcf);
  gemm_bf<<<dim3(4, 8), 256, 0, stream>>>(chunks, nullptr, 1024, 512, 512, 512, Wcb, gxcb);
  repack4<<<dim3(1024, 2), 256, 0, stream>>>(gxcf, gxcb, chk_b_f, chk_b_b, gxcfp, gxcbp);
  // chunk BiLSTM (fwd block 0, bwd block 1)
  chunk_rec<<<2, 1024, 147968, stream>>>(gxcfp, gxcbp, WhPcf, WhPcb, x_len, cho);
  // final FC
  fc_kernel<<<1024, 64, 0, stream>>>(cho, fc_W, fc_b, out);
}

// Round 8
// 908.271 us; speedup vs baseline: 1.6513x; 1.6513x over previous
//
#include <hip/hip_runtime.h>

// ---------------------------------------------------------------------------
// HierarchicalBiLSTM_CRF on MI355X (gfx950) — round 8
//
// Round-8: m-split the recurrent kernels to double active CUs (the r6/r7
// counters show the wall is per-SIMD VALU+issue work on few active CUs;
// weight streaming per CU is m-invariant).
//  - tok_fwd: 64 blocks x 16 seqs (length-sorted groups of 16)
//  - chunk_rec: 4 blocks (2 dir x 2 m-groups of 16)
// Structure per block = r6's best: kt0-1 LDS-resident, kt2 VGPR, kt3-7
// streamed serial 4-frag sections (fits the 128-reg/wave cap at 4 w/SIMD).
// ---------------------------------------------------------------------------

typedef __attribute__((ext_vector_type(8))) short s16x8;
typedef __attribute__((ext_vector_type(4))) float f32x4;
typedef __attribute__((ext_vector_type(2))) unsigned int u32x2;

__device__ __forceinline__ unsigned short f2bf(float f) {
  unsigned u = __builtin_bit_cast(unsigned, f);
  u += 0x7fff + ((u >> 16) & 1);   // RNE
  return (unsigned short)(u >> 16);
}
__device__ __forceinline__ float bf2f(unsigned short h) {
  unsigned u = ((unsigned)h) << 16;
  return __builtin_bit_cast(float, u);
}
__device__ __forceinline__ float sigm(float x) { return 1.f / (1.f + __expf(-x)); }
__device__ __forceinline__ float tanh_(float x) { return 1.f - 2.f / (__expf(2.f * x) + 1.f); }

union PK8 { s16x8 v; unsigned short u[8]; };

// ---------------------------------------------------------------------------
// K0a: cast input-projection weights to bf16 (pad K 300->320 for token Wih)
__global__ void prep_weights(const float* __restrict__ wihf, const float* __restrict__ wihb,
                             const float* __restrict__ wcf, const float* __restrict__ wcb,
                             unsigned short* __restrict__ o_wf, unsigned short* __restrict__ o_wb,
                             unsigned short* __restrict__ o_wcf, unsigned short* __restrict__ o_wcb) {
  const int job = blockIdx.y, r = blockIdx.x, tid = threadIdx.x;
  const float* src; unsigned short* dst; int Ks, Kd;
  switch (job) {
    case 0: src = wihf; dst = o_wf;   Ks = 300; Kd = 320; break;
    case 1: src = wihb; dst = o_wb;   Ks = 300; Kd = 320; break;
    case 2: src = wcf;  dst = o_wcf;  Ks = 512; Kd = 512; break;
    default:src = wcb;  dst = o_wcb;  Ks = 512; Kd = 512; break;
  }
  for (int c = tid; c < Kd; c += 256)
    dst[r * Kd + c] = f2bf(c < Ks ? src[r * Ks + c] : 0.f);
}

// ---------------------------------------------------------------------------
// K0c: repack recurrent weights [1024][256] f32 -> fragment-major bf16.
__global__ __launch_bounds__(256)
void prep_whh_frag(const float* __restrict__ w0, const float* __restrict__ w1,
                   const float* __restrict__ w2,
                   unsigned short* __restrict__ o0, unsigned short* __restrict__ o1,
                   unsigned short* __restrict__ o2) {
  const float* src = blockIdx.y == 0 ? w0 : (blockIdx.y == 1 ? w1 : w2);
  unsigned short* dst = blockIdx.y == 0 ? o0 : (blockIdx.y == 1 ? o1 : o2);
  const int fid = blockIdx.x;
  const int b = fid & 1, g = (fid >> 1) & 3, kt = (fid >> 3) & 7, js = fid >> 6;
  for (int i = threadIdx.x; i < 512; i += 256) {
    const int lane = i >> 3, e = i & 7;
    const int cc = lane & 15, qq = lane >> 4;
    const int row = g * 256 + (js * 2 + b) * 16 + cc;
    const int col = kt * 32 + qq * 8 + e;
    dst[(size_t)fid * 512 + i] = f2bf(src[row * 256 + col]);
  }
}

// ---------------------------------------------------------------------------
__global__ void prep_small(const int* __restrict__ x, const int* __restrict__ xcl,
                           int* __restrict__ clens, int* __restrict__ lastv,
                           int* __restrict__ order, int* __restrict__ glen) {
  __shared__ int start[65];
  const int n = threadIdx.x;  // 1024 threads
  if (n < 65) start[n] = 0;
  __syncthreads();
  int len = xcl[n]; len = len < 1 ? 1 : (len > 64 ? 64 : len);
  clens[n] = len;
  lastv[n] = x[n * 64 + len - 1];
  atomicAdd(&start[len], 1);
  __syncthreads();
  if (n == 0) {
    int acc = 0;
    for (int l = 64; l >= 1; --l) { int h = start[l]; start[l] = acc; acc += h; }
  }
  __syncthreads();
  int pos = atomicAdd(&start[len], 1);
  order[pos] = n;
  __syncthreads();
  if (n < 64) glen[n] = clens[order[n * 16]];   // descending -> 16-group max
}

// ---------------------------------------------------------------------------
// Unified GEMM: C[M][1024](bf16) = A(rows via rowmap)[M][Klog](f32) x B[1024][KP](bf16)^T
__global__ __launch_bounds__(256, 2)
void gemm_bf(const float* __restrict__ A, const int* __restrict__ rowmap,
             int Mrows, int Astride, int Klog, int KP,
             const unsigned short* __restrict__ B, unsigned short* __restrict__ C) {
  __shared__ unsigned short As[128 * 40];
  __shared__ unsigned short Ep[4][64 * 136];
  const int tid = threadIdx.x;
  const int lane = tid & 63, w = tid >> 6;
  const int wrow = w >> 1, wcol = w & 1;
  const int cc = lane & 15, qq = lane >> 4;
  const int m0 = blockIdx.y * 128, n0 = blockIdx.x * 256;

  f32x4 zz = {0.f, 0.f, 0.f, 0.f};
  f32x4 acc[4][8];
#pragma unroll
  for (int i = 0; i < 4; ++i)
#pragma unroll
    for (int j = 0; j < 8; ++j) acc[i][j] = zz;

  const int arow = tid >> 1, ahalf = tid & 1;
  const float* arp = nullptr;
  {
    int av = m0 + arow;
    if (av < Mrows) {
      int amap = rowmap ? rowmap[av] : av;
      arp = A + (long)amap * Astride;
    }
  }

  const int nktiles = KP >> 5;
  for (int kt = 0; kt < nktiles; ++kt) {
    const int k0 = kt << 5;
    __syncthreads();
    {
      const int kb = k0 + ahalf * 16;
      unsigned short hv[16];
      if (arp && kb + 16 <= Klog) {
        const float* p = arp + kb;
#pragma unroll
        for (int i = 0; i < 16; i += 4) {
          f32x4 t = *(const f32x4*)(p + i);
          hv[i] = f2bf(t.x); hv[i + 1] = f2bf(t.y);
          hv[i + 2] = f2bf(t.z); hv[i + 3] = f2bf(t.w);
        }
      } else {
#pragma unroll
        for (int i = 0; i < 16; ++i) {
          float v = (arp && (kb + i) < Klog) ? arp[kb + i] : 0.f;
          hv[i] = f2bf(v);
        }
      }
      PK8 p0, p1;
#pragma unroll
      for (int i = 0; i < 8; ++i) { p0.u[i] = hv[i]; p1.u[i] = hv[8 + i]; }
      *(s16x8*)&As[arow * 40 + ahalf * 16] = p0.v;
      *(s16x8*)&As[arow * 40 + ahalf * 16 + 8] = p1.v;
    }
    __syncthreads();
    s16x8 af[4];
#pragma unroll
    for (int mt = 0; mt < 4; ++mt)
      af[mt] = *(const s16x8*)&As[(wrow * 64 + mt * 16 + cc) * 40 + qq * 8];
#pragma unroll
    for (int nt = 0; nt < 8; ++nt) {
      const unsigned short* bp = B + (long)(n0 + wcol * 128 + nt * 16 + cc) * KP + k0 + qq * 8;
      s16x8 bfr = *(const s16x8*)bp;
#pragma unroll
      for (int mt = 0; mt < 4; ++mt)
        acc[mt][nt] = __builtin_amdgcn_mfma_f32_16x16x32_bf16(af[mt], bfr, acc[mt][nt], 0, 0, 0);
    }
  }
  __syncthreads();
#pragma unroll
  for (int mt = 0; mt < 4; ++mt)
#pragma unroll
    for (int nt = 0; nt < 8; ++nt)
#pragma unroll
      for (int r = 0; r < 4; ++r)
        Ep[w][(mt * 16 + qq * 4 + r) * 136 + nt * 16 + cc] = f2bf(acc[mt][nt][r]);
  __syncthreads();
#pragma unroll
  for (int it = 0; it < 16; ++it) {
    int row = it * 4 + qq;
    s16x8 d = *(const s16x8*)&Ep[w][row * 136 + cc * 8];
    int gm = m0 + wrow * 64 + row;
    int gn = n0 + wcol * 128 + cc * 8;
    if (gm < Mrows) *(s16x8*)&C[(long)gm * 1024 + gn] = d;
  }
}

// ---------------------------------------------------------------------------
__global__ void bwd_step(const unsigned short* __restrict__ gxb,
                         const float* __restrict__ bias,
                         float* __restrict__ chunks) {
  const int n = blockIdx.x, j = threadIdx.x;  // 1024 x 256
  const unsigned short* row = gxb + (long)n * 1024;
  float gi = bf2f(row[j]) + bias[j];
  float gg = bf2f(row[512 + j]) + bias[512 + j];
  float go = bf2f(row[768 + j]) + bias[768 + j];
  float cn = sigm(gi) * tanh_(gg);
  chunks[(long)n * 512 + 256 + j] = sigm(go) * tanh_(cn);
}

// ---------------------------------------------------------------------------
// K4: pre-gather gate projections (gate-packed, bias folded), sorted order,
// T-MAJOR per 16-group: gx[g16][t][m16][j*4+g].
__global__ __launch_bounds__(256)
void gather_gx(const unsigned short* __restrict__ proj, const int* __restrict__ x,
               const int* __restrict__ order, const int* __restrict__ clens,
               const int* __restrict__ glen, const float* __restrict__ bias,
               unsigned short* __restrict__ gx) {
  const int t = blockIdx.x, p = blockIdx.y, j = threadIdx.x;
  if (t >= glen[p >> 4]) return;
  const int seq = order[p];
  const int len = clens[seq];
  unsigned short* dst = gx + (((size_t)(p >> 4) * 64 + t) * 16 + (p & 15)) * 1024 + j * 4;
  if (t >= len) { u32x2 z = {0u, 0u}; *(u32x2*)dst = z; return; }
  const int tok = x[seq * 64 + t];
  const unsigned short* src = proj + (size_t)tok * 1024 + j;
  unsigned v0 = f2bf(bf2f(src[0]) + bias[j]);
  unsigned v1 = f2bf(bf2f(src[256]) + bias[256 + j]);
  unsigned v2 = f2bf(bf2f(src[512]) + bias[512 + j]);
  unsigned v3 = f2bf(bf2f(src[768]) + bias[768 + j]);
  u32x2 pk = {v0 | (v1 << 16), v2 | (v3 << 16)};
  *(u32x2*)dst = pk;
}

// ---------------------------------------------------------------------------
// K6b: gate-pack gxc with bias folded, T-MAJOR per 16-group:
// dst[((mg*32+t)*16 + m16)] from src[m*32+t], m = mg*16+m16.
__global__ __launch_bounds__(256)
void repack4(const unsigned short* __restrict__ s0, const unsigned short* __restrict__ s1,
             const float* __restrict__ b0, const float* __restrict__ b1,
             unsigned short* __restrict__ d0, unsigned short* __restrict__ d1) {
  const int r = blockIdx.x, j = threadIdx.x;
  const int m = r >> 5, t = r & 31;
  const int mg = m >> 4, m16 = m & 15;
  const unsigned short* s = (blockIdx.y ? s1 : s0) + (size_t)r * 1024;
  const float* bb = blockIdx.y ? b1 : b0;
  unsigned short* d = (blockIdx.y ? d1 : d0) +
                      (size_t)((mg * 32 + t) * 16 + m16) * 1024 + j * 4;
  unsigned v0 = f2bf(bf2f(s[j]) + bb[j]);
  unsigned v1 = f2bf(bf2f(s[256 + j]) + bb[256 + j]);
  unsigned v2 = f2bf(bf2f(s[512 + j]) + bb[512 + j]);
  unsigned v3 = f2bf(bf2f(s[768 + j]) + bb[768 + j]);
  u32x2 pk = {v0 | (v1 << 16), v2 | (v3 << 16)};
  *(u32x2*)d = pk;
}

// ---------------------------------------------------------------------------
// K5: forward token LSTM. 64 blocks x 16 seqs x 1024 threads (16 waves).
// Wave w: j = w*16+cc, single m-tile (16 seqs). kt0-1 LDS / kt2 VGPR /
// kt3-7 streamed serial sections.
__global__ __launch_bounds__(1024, 4)
void tok_fwd(const unsigned short* __restrict__ gx,     // [g16][64][16][1024]
             const unsigned short* __restrict__ WhP,    // fragment-major
             const int* __restrict__ order,
             const int* __restrict__ clens,
             const int* __restrict__ glen,
             float* __restrict__ chunks) {
  extern __shared__ unsigned short smem[];
  unsigned short* hly = smem;                 // [16][264] = 4224 shorts
  unsigned short* ldsW = smem + 4224;         // 16 waves * 4096 shorts (128 KB)
  int* sg = (int*)(smem + 69760);             // [16]
  int* slen = sg + 16;                        // [16]

  const int tid = threadIdx.x;
  const int lane = tid & 63, w = tid >> 6;
  const int cc = lane & 15, qq = lane >> 4;
  const int gb = blockIdx.x;

  if (tid < 16) {
    int s = order[gb * 16 + tid];
    sg[tid] = s;
    slen[tid] = clens[s];
  }
  for (int i = tid; i < 4224; i += 1024) hly[i] = 0;

  const unsigned short* wgl = WhP + ((size_t)(w >> 1) * 64 + (w & 1)) * 512 + lane * 8;
  // LDS-resident kt0-1 (8 frags/wave)
  {
    unsigned short* ld = ldsW + w * 4096 + lane * 8;
#pragma unroll
    for (int kt = 0; kt < 2; ++kt)
#pragma unroll
      for (int g = 0; g < 4; ++g)
        *(s16x8*)&ld[(kt * 4 + g) * 512] = *(const s16x8*)&wgl[(kt * 8 + g * 2) * 512];
  }
  // VGPR-resident kt2 (4 frags)
  s16x8 Rw[4];
#pragma unroll
  for (int g = 0; g < 4; ++g) Rw[g] = *(const s16x8*)&wgl[(16 + g * 2) * 512];

  __syncthreads();

  const int maxlen = glen[gb];
  const int j = w * 16 + cc;
  int lenr[4];
#pragma unroll
  for (int r = 0; r < 4; ++r) lenr[r] = slen[qq * 4 + r];

  float cst[4];
#pragma unroll
  for (int r = 0; r < 4; ++r) cst[r] = 0.f;

  const unsigned short* gx0 = gx + (size_t)gb * 64 * 16 * 1024 + j * 4;
  const unsigned short* ldw = ldsW + w * 4096 + lane * 8;
  f32x4 zz = {0.f, 0.f, 0.f, 0.f};

  for (int t = 0; t < maxlen; ++t) {
    __syncthreads();   // A: prev-step h writes visible

    // gx loads for this step — issued early, consumed in epilogue
    u32x2 gxp[4];
#pragma unroll
    for (int r = 0; r < 4; ++r) {
      const int m = qq * 4 + r;
      gxp[r] = *(const u32x2*)(gx0 + ((size_t)t * 16 + m) * 1024);
    }

    f32x4 acc[4];
#pragma unroll
    for (int g = 0; g < 4; ++g) acc[g] = zz;

    // kt0-1: LDS-resident weights
#pragma unroll
    for (int kt = 0; kt < 2; ++kt) {
      s16x8 a0 = *(const s16x8*)&hly[cc * 264 + kt * 32 + qq * 8];
#pragma unroll
      for (int g = 0; g < 4; ++g) {
        s16x8 bf = *(const s16x8*)&ldw[(kt * 4 + g) * 512];
        acc[g] = __builtin_amdgcn_mfma_f32_16x16x32_bf16(a0, bf, acc[g], 0, 0, 0);
      }
    }
    // kt2: VGPR-resident
    {
      s16x8 a0 = *(const s16x8*)&hly[cc * 264 + 2 * 32 + qq * 8];
#pragma unroll
      for (int g = 0; g < 4; ++g)
        acc[g] = __builtin_amdgcn_mfma_f32_16x16x32_bf16(a0, Rw[g], acc[g], 0, 0, 0);
    }
    // kt3-7: streamed serially (one 4-frag section in flight)
#pragma unroll 1
    for (int kt = 3; kt < 8; ++kt) {
      s16x8 Sb[4];
#pragma unroll
      for (int g = 0; g < 4; ++g)
        Sb[g] = *(const s16x8*)&wgl[(kt * 8 + g * 2) * 512];
      s16x8 a0 = *(const s16x8*)&hly[cc * 264 + kt * 32 + qq * 8];
#pragma unroll
      for (int g = 0; g < 4; ++g)
        acc[g] = __builtin_amdgcn_mfma_f32_16x16x32_bf16(a0, Sb[g], acc[g], 0, 0, 0);
    }

    __syncthreads();   // B: MFMA h reads done

#pragma unroll
    for (int r = 0; r < 4; ++r) {
      const int m = qq * 4 + r;
      const u32x2 pk = gxp[r];
      float gi = acc[0][r] + bf2f((unsigned short)(pk.x & 0xffff));
      float gf = acc[1][r] + bf2f((unsigned short)(pk.x >> 16));
      float gg = acc[2][r] + bf2f((unsigned short)(pk.y & 0xffff));
      float go = acc[3][r] + bf2f((unsigned short)(pk.y >> 16));
      if (t < lenr[r]) {
        float cn = sigm(gf) * cst[r] + sigm(gi) * tanh_(gg);
        cst[r] = cn;
        float hn = sigm(go) * tanh_(cn);
        hly[m * 264 + j] = f2bf(hn);
      }
    }
  }

  __syncthreads();
  // final h (frozen in hly at each sequence's last valid step) -> chunks f32
#pragma unroll
  for (int r = 0; r < 4; ++r) {
    const int m = qq * 4 + r;
    chunks[(size_t)sg[m] * 512 + j] = bf2f(hly[m * 264 + j]);
  }
}

// ---------------------------------------------------------------------------
// K7: chunk BiLSTM. 4 blocks (2 dir x 2 m-groups of 16) x 1024 threads.
__global__ __launch_bounds__(1024, 4)
void chunk_rec(const unsigned short* __restrict__ gxf,   // t-major [mg][32][16][1024]
               const unsigned short* __restrict__ gxb,
               const unsigned short* __restrict__ WhPf,
               const unsigned short* __restrict__ WhPb,
               const int* __restrict__ xlen,
               unsigned short* __restrict__ ch) {
  extern __shared__ unsigned short smem[];
  unsigned short* hly = smem;                 // 4224 shorts
  unsigned short* ldsW = smem + 4224;         // 65536 shorts

  const int tid = threadIdx.x;
  const int lane = tid & 63, w = tid >> 6;
  const int cc = lane & 15, qq = lane >> 4;
  const int dir = blockIdx.x & 1, mg = blockIdx.x >> 1;
  const unsigned short* gx = (dir ? gxb : gxf) + (size_t)mg * 32 * 16 * 1024;
  const unsigned short* WhP = dir ? WhPb : WhPf;

  for (int i = tid; i < 4224; i += 1024) hly[i] = 0;

  const unsigned short* wgl = WhP + ((size_t)(w >> 1) * 64 + (w & 1)) * 512 + lane * 8;
  {
    unsigned short* ld = ldsW + w * 4096 + lane * 8;
#pragma unroll
    for (int kt = 0; kt < 2; ++kt)
#pragma unroll
      for (int g = 0; g < 4; ++g)
        *(s16x8*)&ld[(kt * 4 + g) * 512] = *(const s16x8*)&wgl[(kt * 8 + g * 2) * 512];
  }
  s16x8 Rw[4];
#pragma unroll
  for (int g = 0; g < 4; ++g) Rw[g] = *(const s16x8*)&wgl[(16 + g * 2) * 512];

  __syncthreads();

  const int j = w * 16 + cc;
  int lenr[4];
#pragma unroll
  for (int r = 0; r < 4; ++r) {
    int L = xlen[mg * 16 + qq * 4 + r];
    lenr[r] = L > 32 ? 32 : L;
  }

  float cst[4];
#pragma unroll
  for (int r = 0; r < 4; ++r) cst[r] = 0.f;

  const unsigned short* ldw = ldsW + w * 4096 + lane * 8;
  f32x4 zz = {0.f, 0.f, 0.f, 0.f};

  for (int tt = 0; tt < 32; ++tt) {
    const int t = dir ? (31 - tt) : tt;

    __syncthreads();

    u32x2 gxp[4];
#pragma unroll
    for (int r = 0; r < 4; ++r) {
      const int m = qq * 4 + r;
      gxp[r] = *(const u32x2*)(gx + ((size_t)t * 16 + m) * 1024 + j * 4);
    }

    f32x4 acc[4];
#pragma unroll
    for (int g = 0; g < 4; ++g) acc[g] = zz;

#pragma unroll
    for (int kt = 0; kt < 2; ++kt) {
      s16x8 a0 = *(const s16x8*)&hly[cc * 264 + kt * 32 + qq * 8];
#pragma unroll
      for (int g = 0; g < 4; ++g) {
        s16x8 bf = *(const s16x8*)&ldw[(kt * 4 + g) * 512];
        acc[g] = __builtin_amdgcn_mfma_f32_16x16x32_bf16(a0, bf, acc[g], 0, 0, 0);
      }
    }
    {
      s16x8 a0 = *(const s16x8*)&hly[cc * 264 + 2 * 32 + qq * 8];
#pragma unroll
      for (int g = 0; g < 4; ++g)
        acc[g] = __builtin_amdgcn_mfma_f32_16x16x32_bf16(a0, Rw[g], acc[g], 0, 0, 0);
    }
#pragma unroll 1
    for (int kt = 3; kt < 8; ++kt) {
      s16x8 Sb[4];
#pragma unroll
      for (int g = 0; g < 4; ++g)
        Sb[g] = *(const s16x8*)&wgl[(kt * 8 + g * 2) * 512];
      s16x8 a0 = *(const s16x8*)&hly[cc * 264 + kt * 32 + qq * 8];
#pragma unroll
      for (int g = 0; g < 4; ++g)
        acc[g] = __builtin_amdgcn_mfma_f32_16x16x32_bf16(a0, Sb[g], acc[g], 0, 0, 0);
    }

    __syncthreads();

#pragma unroll
    for (int r = 0; r < 4; ++r) {
      const int m = qq * 4 + r;
      const u32x2 pk = gxp[r];
      float gi = acc[0][r] + bf2f((unsigned short)(pk.x & 0xffff));
      float gf = acc[1][r] + bf2f((unsigned short)(pk.x >> 16));
      float gg = acc[2][r] + bf2f((unsigned short)(pk.y & 0xffff));
      float go = acc[3][r] + bf2f((unsigned short)(pk.y >> 16));
      unsigned short hb16 = 0;
      if (t < lenr[r]) {
        float cn = sigm(gf) * cst[r] + sigm(gi) * tanh_(gg);
        cst[r] = cn;
        float hn = sigm(go) * tanh_(cn);
        hb16 = f2bf(hn);
        hly[m * 264 + j] = hb16;
      }
      ch[(size_t)((mg * 16 + m) * 32 + t) * 512 + dir * 256 + j] = hb16;
    }
  }
}

// ---------------------------------------------------------------------------
__global__ __launch_bounds__(64)
void fc_kernel(const unsigned short* __restrict__ ch, const float* __restrict__ W,
               const float* __restrict__ bfc, float* __restrict__ out) {
  const int n = blockIdx.x, lane = threadIdx.x;
  float xv[8];
  const unsigned short* cp = ch + (long)n * 512 + lane * 8;
#pragma unroll
  for (int i = 0; i < 8; ++i) xv[i] = bf2f(cp[i]);
  float s[9];
#pragma unroll
  for (int k = 0; k < 9; ++k) {
    const float* wr = W + k * 512 + lane * 8;
    float t = 0.f;
#pragma unroll
    for (int i = 0; i < 8; ++i) t += xv[i] * wr[i];
    s[k] = t;
  }
#pragma unroll
  for (int off = 32; off; off >>= 1)
#pragma unroll
    for (int k = 0; k < 9; ++k) s[k] += __shfl_down(s[k], off, 64);
  if (lane == 0) {
#pragma unroll
    for (int k = 0; k < 9; ++k) out[n * 9 + k] = s[k] + bfc[k];
  }
}

// ---------------------------------------------------------------------------
extern "C" void kernel_launch(void* const* d_in, const int* in_sizes, int n_in,
                              void* d_out, int out_size, void* d_ws, size_t ws_size,
                              hipStream_t stream) {
  const int*   x           = (const int*)d_in[0];
  const int*   x_len       = (const int*)d_in[2];
  const int*   x_chunk_len = (const int*)d_in[3];
  const float* emb         = (const float*)d_in[4];
  const float* tok_Wih_f   = (const float*)d_in[5];
  const float* tok_Whh_f   = (const float*)d_in[6];
  const float* tok_b_f     = (const float*)d_in[7];
  const float* tok_Wih_b   = (const float*)d_in[8];
  // d_in[9] tok_Whh_b: unused (reverse masked scan at t=clen-1 starts from zero state)
  const float* tok_b_b     = (const float*)d_in[10];
  const float* chk_Wih_f   = (const float*)d_in[11];
  const float* chk_Whh_f   = (const float*)d_in[12];
  const float* chk_b_f     = (const float*)d_in[13];
  const float* chk_Wih_b   = (const float*)d_in[14];
  const float* chk_Whh_b   = (const float*)d_in[15];
  const float* chk_b_b     = (const float*)d_in[16];
  const float* fc_W        = (const float*)d_in[17];
  const float* fc_b        = (const float*)d_in[18];
  float* out = (float*)d_out;

  char* ws = (char*)d_ws;
  size_t off = 0;
  auto alloc = [&](size_t bytes) -> void* {
    void* p = ws + off;
    off += (bytes + 255) & ~(size_t)255;
    return p;
  };
  unsigned short* Wf   = (unsigned short*)alloc((size_t)1024 * 320 * 2);
  unsigned short* Wb   = (unsigned short*)alloc((size_t)1024 * 320 * 2);
  unsigned short* Wcf  = (unsigned short*)alloc((size_t)1024 * 512 * 2);
  unsigned short* Wcb  = (unsigned short*)alloc((size_t)1024 * 512 * 2);
  unsigned short* WhPtok=(unsigned short*)alloc((size_t)512 * 512 * 2);   // frag-major
  unsigned short* WhPcf= (unsigned short*)alloc((size_t)512 * 512 * 2);
  unsigned short* WhPcb= (unsigned short*)alloc((size_t)512 * 512 * 2);
  unsigned short* proj = (unsigned short*)alloc((size_t)30000 * 1024 * 2);
  unsigned short* gxbb = (unsigned short*)alloc((size_t)1024 * 1024 * 2);
  unsigned short* gxcf = (unsigned short*)alloc((size_t)1024 * 1024 * 2);
  unsigned short* gxcb = (unsigned short*)alloc((size_t)1024 * 1024 * 2);
  unsigned short* gxcfp= (unsigned short*)alloc((size_t)1024 * 1024 * 2);
  unsigned short* gxcbp= (unsigned short*)alloc((size_t)1024 * 1024 * 2);
  float*          chunks = (float*)alloc((size_t)1024 * 512 * 4);
  unsigned short* cho  = (unsigned short*)alloc((size_t)1024 * 512 * 2);
  unsigned short* gxs  = (unsigned short*)alloc((size_t)1024 * 64 * 1024 * 2);  // 134 MB
  int* clens = (int*)alloc(1024 * 4);
  int* lastv = (int*)alloc(1024 * 4);
  int* order = (int*)alloc(1024 * 4);
  int* glen  = (int*)alloc(64 * 4);

  // allow >64 KB dynamic LDS for the recurrent kernels (gfx950: 160 KB/CU)
  hipFuncSetAttribute((const void*)tok_fwd,
                      hipFuncAttributeMaxDynamicSharedMemorySize, 139776);
  hipFuncSetAttribute((const void*)chunk_rec,
                      hipFuncAttributeMaxDynamicSharedMemorySize, 139520);

  prep_weights<<<dim3(1024, 4), 256, 0, stream>>>(
      tok_Wih_f, tok_Wih_b, chk_Wih_f, chk_Wih_b, Wf, Wb, Wcf, Wcb);
  prep_whh_frag<<<dim3(512, 3), 256, 0, stream>>>(
      tok_Whh_f, chk_Whh_f, chk_Whh_b, WhPtok, WhPcf, WhPcb);
  prep_small<<<1, 1024, 0, stream>>>(x, x_chunk_len, clens, lastv, order, glen);

  // vocab pre-projection: proj = emb x tok_Wih_f^T
  gemm_bf<<<dim3(4, 235), 256, 0, stream>>>(emb, nullptr, 30000, 300, 300, 320, Wf, proj);
  // backward gx for last tokens only
  gemm_bf<<<dim3(4, 8), 256, 0, stream>>>(emb, lastv, 1024, 300, 300, 320, Wb, gxbb);
  bwd_step<<<1024, 256, 0, stream>>>(gxbb, tok_b_b, chunks);
  // pre-gather forward gate projections (gate-packed, bias folded, t-major/16)
  gather_gx<<<dim3(64, 1024), 256, 0, stream>>>(proj, x, order, clens, glen, tok_b_f, gxs);
  // forward token recurrence: 64 blocks x 16 seqs
  tok_fwd<<<64, 1024, 139776, stream>>>(gxs, WhPtok, order, clens, glen, chunks);
  // chunk-level input projections
  gemm_bf<<<dim3(4, 8), 256, 0, stream>>>(chunks, nullptr, 1024, 512, 512, 512, Wcf, gxcf);
  gemm_bf<<<dim3(4, 8), 256, 0, stream>>>(chunks, nullptr, 1024, 512, 512, 512, Wcb, gxcb);
  repack4<<<dim3(1024, 2), 256, 0, stream>>>(gxcf, gxcb, chk_b_f, chk_b_b, gxcfp, gxcbp);
  // chunk BiLSTM: 4 blocks (2 dir x 2 m-groups)
  chunk_rec<<<4, 1024, 139520, stream>>>(gxcfp, gxcbp, WhPcf, WhPcb, x_len, cho);
  // final FC
  fc_kernel<<<1024, 64, 0, stream>>>(cho, fc_W, fc_b, out);
}